// Round 7
// baseline (215.363 us; speedup 1.0000x reference)
//
#include <hip/hip_runtime.h>
#include <hip/hip_bf16.h>

#define N_NODES 50000
#define N_EDGES 400000
#define DIM     128
#define NREL    8
#define NBASES  4
#define PLANE   ((long long)N_NODES * DIM)

typedef __hip_bfloat16 bf16;

typedef __bf16 bf16x8 __attribute__((ext_vector_type(8)));
typedef float  f32x4  __attribute__((ext_vector_type(4)));

union frag_u { bf16x8 v; bf16 e[8]; };
union pack4_u { unsigned long long ll; bf16 b[4]; };

// ---- workspace layout (bytes) ----
// Hr   bf16 [NREL][N][D] : 102,400,000  (relation-projected nodes, wc folded)
// hb16 bf16 [N][D]       :  12,800,000
// recs uint2 [E]         :   3,200,000  (key=(src<<3)|et, bits(norm))
// base int [N+1] pad     :     200,064
// cur  int [N]   pad     :     200,064
// WrT  bf16 [NREL][D][D] :     262,144  (WrT[r][o][i] = W_r[i][o])
// lwT  bf16 [D][D]       :      32,768
// fwTb bf16 [D][D]       :      32,768
#define HR_OFF    0LL
#define HB16_OFF  102400000LL
#define RECS_OFF  115200000LL
#define BASE_OFF  118400000LL
#define CUR_OFF   118600064LL
#define WRT_OFF   118800128LL
#define LWT_OFF   119062272LL
#define FWT_OFF   119095040LL
#define WS_NEEDED 119127808LL

__device__ __forceinline__ int swzb(int row) { return (row & 15) << 4; }  // 256B rows
__device__ __forceinline__ int swzy(int row) { return (row & 31) << 4; }  // 512B rows

// ---------------------------------------------------------------------------
// K_prep: hb16 = bf16(h); WrT[r][o][i] = bf16(sum_b wc[r,b]V[b][i][o]);
//         lwT/fwTb; in-degree histogram. cur pre-zeroed by memsetAsync.
__global__ __launch_bounds__(256)
void k_prep(const float* __restrict__ h, const float* __restrict__ V,
            const float* __restrict__ wc,
            const float* __restrict__ loop_w, const float* __restrict__ ffn_w,
            const int* __restrict__ dst,
            bf16* __restrict__ hb, bf16* __restrict__ WrT,
            bf16* __restrict__ lwT, bf16* __restrict__ fwTb,
            int* __restrict__ cur) {
    int p = blockIdx.x * 256 + threadIdx.x;
    if (p < N_NODES * DIM / 8) {
        const float* s = h + (long long)p * 8;
        f32x4 lo = *(const f32x4*)s, hi = *(const f32x4*)(s + 4);
        frag_u o;
#pragma unroll
        for (int j = 0; j < 4; ++j) {
            o.e[j]     = __float2bfloat16(lo[j]);
            o.e[4 + j] = __float2bfloat16(hi[j]);
        }
        *(bf16x8*)(hb + (long long)p * 8) = o.v;
    }
    if (p < N_EDGES) atomicAdd(&cur[dst[p]], 1);
    if (p < NREL * DIM * DIM) {
        int r = p >> 14, rem = p & 16383, i = rem >> 7, o = rem & 127;
        float acc = 0.f;
#pragma unroll
        for (int b = 0; b < NBASES; ++b)
            acc += wc[r * NBASES + b] * V[b * DIM * DIM + rem];
        WrT[(r << 14) + o * DIM + i] = __float2bfloat16(acc);
    }
    if (p < DIM * DIM) {
        lwT[p]  = __float2bfloat16(loop_w[(p & 127) * DIM + (p >> 7)]);
        fwTb[p] = __float2bfloat16(ffn_w[p]);
    }
}

// ---------------------------------------------------------------------------
// K_scan: exclusive prefix sum of cur -> base; cur <- base. 1 block.
#define SCAN_V 13
__global__ __launch_bounds__(1024)
void k_scan(int* __restrict__ cur, int* __restrict__ base) {
    __shared__ int wsum[16];
    const int t = threadIdx.x, lane = t & 63, wv = t >> 6;
    const int i0 = t * (SCAN_V * 4);
    int4 v[SCAN_V];
#pragma unroll
    for (int i = 0; i < SCAN_V; ++i) {
        int idx = i0 + i * 4;
        if (idx + 3 < N_NODES) v[i] = *(const int4*)(cur + idx);
        else {
            v[i].x = (idx + 0 < N_NODES) ? cur[idx + 0] : 0;
            v[i].y = (idx + 1 < N_NODES) ? cur[idx + 1] : 0;
            v[i].z = (idx + 2 < N_NODES) ? cur[idx + 2] : 0;
            v[i].w = (idx + 3 < N_NODES) ? cur[idx + 3] : 0;
        }
    }
    int s = 0;
#pragma unroll
    for (int i = 0; i < SCAN_V; ++i) s += v[i].x + v[i].y + v[i].z + v[i].w;
    int inc = s;
#pragma unroll
    for (int m = 1; m < 64; m <<= 1) {
        int u = __shfl_up(inc, m);
        if (lane >= m) inc += u;
    }
    if (lane == 63) wsum[wv] = inc;
    __syncthreads();
    if (t < 16) {
        int w = wsum[t];
        int winc = w;
#pragma unroll
        for (int m = 1; m < 16; m <<= 1) {
            int u = __shfl_up(winc, m);
            if (t >= m) winc += u;
        }
        wsum[t] = winc - w;
    }
    __syncthreads();
    int run = wsum[wv] + (inc - s);
#pragma unroll
    for (int i = 0; i < SCAN_V; ++i) {
        int idx = i0 + i * 4;
        if (idx + 3 < N_NODES) {
            int4 o;
            o.x = run; o.y = o.x + v[i].x; o.z = o.y + v[i].y; o.w = o.z + v[i].z;
            run = o.w + v[i].w;
            *(int4*)(base + idx) = o;
            *(int4*)(cur + idx) = o;
        } else {
            if (idx + 0 < N_NODES) { base[idx+0] = run; cur[idx+0] = run; run += v[i].x; }
            if (idx + 1 < N_NODES) { base[idx+1] = run; cur[idx+1] = run; run += v[i].y; }
            if (idx + 2 < N_NODES) { base[idx+2] = run; cur[idx+2] = run; run += v[i].z; }
            if (idx + 3 < N_NODES) { base[idx+3] = run; cur[idx+3] = run; run += v[i].w; }
        }
    }
    if (t == 1023) base[N_NODES] = run;
}

// ---------------------------------------------------------------------------
// K_scatter: bucket edges by dst; recs = {(src<<3)|et, bits(norm)}.
__global__ __launch_bounds__(256)
void k_scatter(const int* __restrict__ src, const int* __restrict__ dst,
               const int* __restrict__ et, const float* __restrict__ norm,
               int* __restrict__ cur, uint2* __restrict__ recs) {
    int e = blockIdx.x * 256 + threadIdx.x;
    if (e >= N_EDGES) return;
    int d = dst[e];
    int pos = atomicAdd(&cur[d], 1);
    uint2 rc;
    rc.x = ((unsigned)src[e] << 3) | (unsigned)et[e];
    rc.y = __float_as_uint(norm[e]);
    recs[pos] = rc;
}

// ---------------------------------------------------------------------------
// K_gemm (MFMA): Hr[r] = bf16(h @ W_r). Block = 128 rows x 1 relation.
// A direct from hb16 global; LDS-staged epilogue for 1KB-coalesced stores.
__global__ __launch_bounds__(256)
void k_gemm(const bf16* __restrict__ hb, const bf16* __restrict__ WrT,
            bf16* __restrict__ Hr) {
    __shared__ __align__(16) char ostage[4][8192];
    const int t   = threadIdx.x;
    const int wid = t >> 6;
    const int l   = t & 63;
    const int n0  = blockIdx.x * 128;
    const int rel = blockIdx.y;

    const int lrow = l & 15;
    const int kgrp = l >> 4;
    const bf16* Bsrc = WrT + (rel << 14);

    f32x4 acc[2][8];
#pragma unroll
    for (int mt = 0; mt < 2; ++mt)
#pragma unroll
        for (int nt = 0; nt < 8; ++nt)
            acc[mt][nt] = f32x4{0.f, 0.f, 0.f, 0.f};

#pragma unroll
    for (int ks = 0; ks < 4; ++ks) {
        frag_u a[2];
#pragma unroll
        for (int mt = 0; mt < 2; ++mt) {
            int row = n0 + wid * 32 + mt * 16 + lrow;
            row = row < N_NODES ? row : N_NODES - 1;
            a[mt].v = *(const bf16x8*)(hb + (long long)row * DIM + ks * 32 + kgrp * 8);
        }
        frag_u b[8];
#pragma unroll
        for (int nt = 0; nt < 8; ++nt)
            b[nt].v = *(const bf16x8*)(Bsrc + (nt * 16 + lrow) * DIM +
                                       ks * 32 + kgrp * 8);
#pragma unroll
        for (int mt = 0; mt < 2; ++mt)
#pragma unroll
            for (int nt = 0; nt < 8; ++nt)
                acc[mt][nt] = __builtin_amdgcn_mfma_f32_16x16x32_bf16(
                    b[nt].v, a[mt].v, acc[mt][nt], 0, 0, 0);
    }

    char* os = ostage[wid];
#pragma unroll
    for (int mt = 0; mt < 2; ++mt) {
        int r = mt * 16 + lrow;
#pragma unroll
        for (int nt = 0; nt < 8; ++nt) {
            pack4_u p;
#pragma unroll
            for (int j = 0; j < 4; ++j)
                p.b[j] = __float2bfloat16(acc[mt][nt][j]);
            int byte = (r * 256 + (nt * 16 + kgrp * 4) * 2) ^ swzb(r);
            *(unsigned long long*)(os + byte) = p.ll;
        }
    }
    __builtin_amdgcn_s_waitcnt(0);
#pragma unroll
    for (int it = 0; it < 8; ++it) {
        int flat = it * 1024 + l * 16;
        int r = flat >> 8, cbyte = flat & 255;
        int byte = (r * 256 + cbyte) ^ swzb(r);
        bf16x8 vv = *(const bf16x8*)(os + byte);
        int grow = n0 + wid * 32 + r;
        if (grow < N_NODES)
            *(bf16x8*)((char*)(Hr + (long long)rel * PLANE +
                               (long long)grow * DIM) + cbyte) = vv;
    }
}

// ---------------------------------------------------------------------------
// K_final: 32 nodes/block, 256 thr (4 waves), LDS 24 KB -> 6 blocks/CU.
//   B: metadata-batched CSR gather (<=16 edge recs loaded coalesced per node;
//      each 16-lane group issues up to 4 INDEPENDENT Hr row loads) -> aggy
//   C: MFMA1 hn = relu(h@loop_w + agg + bias)  (A from hb16 global) -> hnb
//   D: MFMA2 y = hn@ffn_w^T + ffn_b + h        -> aggy (reused)
//   E: LayerNorm -> out
__global__ __launch_bounds__(256, 6)
void k_final(const bf16* __restrict__ hb16, const bf16* __restrict__ Hr,
             const uint2* __restrict__ recs, const int* __restrict__ base,
             const bf16* __restrict__ lwT, const float* __restrict__ bias,
             const bf16* __restrict__ fwTb, const float* __restrict__ ffn_b,
             const float* __restrict__ ln_g, const float* __restrict__ ln_b,
             float* __restrict__ out) {
    __shared__ __align__(16) char aggy[32 * 512];   // 16 KB f32 swz (agg, then y)
    __shared__ __align__(16) char hnb[32 * 256];    // 8 KB bf16 swz
    const int t = threadIdx.x, wv = t >> 6, l = t & 63;
    const int n0 = blockIdx.x * 32;
    const int g = l >> 4, c = l & 15;

    // ---- B: gather. wave wv: nodes 8wv..8wv+7. Per node: one coalesced
    //         16-record metadata load, then group g handles edges g+4k. ----
#pragma unroll 1
    for (int jj = 0; jj < 8; ++jj) {
        const int row = wv * 8 + jj;
        const int n = n0 + row;
        float acc[8];
#pragma unroll
        for (int q = 0; q < 8; ++q) acc[q] = 0.f;
        if (n < N_NODES) {
            const int b0 = base[n], b1 = base[n + 1];
#pragma unroll 1
            for (int eb = b0; eb < b1; eb += 16) {
                const int nm = b1 - eb;
                uint2 md = (c < nm) ? recs[eb + c] : uint2{0u, 0u};
#pragma unroll
                for (int k = 0; k < 4; ++k) {
                    const int slot = g + 4 * k;
                    const int  skey = __shfl((int)md.x, slot);
                    const float w   = __uint_as_float(__shfl((int)md.y, slot));
                    if (slot < nm) {
                        const long long off =
                            ((long long)(skey & 7) * N_NODES + (skey >> 3)) * DIM;
                        frag_u f;
                        f.v = *((const bf16x8*)(Hr + off) + c);
#pragma unroll
                        for (int q = 0; q < 8; ++q)
                            acc[q] = fmaf(__bfloat162float(f.e[q]), w, acc[q]);
                    }
                }
            }
        }
#pragma unroll
        for (int q = 0; q < 8; ++q) {
            acc[q] += __shfl_xor(acc[q], 16);
            acc[q] += __shfl_xor(acc[q], 32);
        }
        if (g == 0) {
            const int x = swzy(row);
            f32x4 lo{acc[0], acc[1], acc[2], acc[3]};
            f32x4 hi{acc[4], acc[5], acc[6], acc[7]};
            *(f32x4*)(aggy + row * 512 + ((c * 32) ^ x)) = lo;
            *(f32x4*)(aggy + row * 512 + ((c * 32 + 16) ^ x)) = hi;
        }
    }
    __syncthreads();

    // ---- C: MFMA1: hn = relu(h @ loop_w + agg + bias) ----
    const int lrow = l & 15, kgrp = l >> 4;
    const int rw = (wv & 1) * 16, cb = (wv >> 1) * 64;
    const int arow = rw + lrow;
    const int grow = n0 + arow;
    const long long growc = (grow < N_NODES) ? grow : (N_NODES - 1);
    {
        f32x4 acc1[4];
#pragma unroll
        for (int nt = 0; nt < 4; ++nt) acc1[nt] = f32x4{0.f, 0.f, 0.f, 0.f};
#pragma unroll
        for (int ks = 0; ks < 4; ++ks) {
            frag_u a;
            a.v = *(const bf16x8*)(hb16 + growc * DIM + ks * 32 + kgrp * 8);
#pragma unroll
            for (int nt = 0; nt < 4; ++nt) {
                frag_u b;
                b.v = *(const bf16x8*)(lwT + (cb + nt * 16 + lrow) * DIM +
                                       ks * 32 + kgrp * 8);
                acc1[nt] = __builtin_amdgcn_mfma_f32_16x16x32_bf16(
                    b.v, a.v, acc1[nt], 0, 0, 0);
            }
        }
        const int xb = swzb(arow), xy = swzy(arow);
#pragma unroll
        for (int nt = 0; nt < 4; ++nt) {
            int col = cb + nt * 16 + kgrp * 4;
            f32x4 ag = *(const f32x4*)(aggy + arow * 512 + ((col * 4) ^ xy));
            f32x4 bi = *(const f32x4*)(bias + col);
            pack4_u p;
#pragma unroll
            for (int j = 0; j < 4; ++j)
                p.b[j] = __float2bfloat16(fmaxf(acc1[nt][j] + ag[j] + bi[j], 0.f));
            *(unsigned long long*)(hnb + ((arow * 256 + col * 2) ^ xb)) = p.ll;
        }
    }
    __syncthreads();

    // ---- D: MFMA2: y = hn @ ffn_w^T + ffn_b + h ----
    {
        f32x4 acc2[4];
#pragma unroll
        for (int nt = 0; nt < 4; ++nt) acc2[nt] = f32x4{0.f, 0.f, 0.f, 0.f};
#pragma unroll
        for (int ks = 0; ks < 4; ++ks) {
            frag_u a;
            int abyte = (arow * 256 + ks * 64 + kgrp * 16) ^ swzb(arow);
            a.v = *(const bf16x8*)(hnb + abyte);
#pragma unroll
            for (int nt = 0; nt < 4; ++nt) {
                frag_u b;
                b.v = *(const bf16x8*)(fwTb + (cb + nt * 16 + lrow) * DIM +
                                       ks * 32 + kgrp * 8);
                acc2[nt] = __builtin_amdgcn_mfma_f32_16x16x32_bf16(
                    b.v, a.v, acc2[nt], 0, 0, 0);
            }
        }
        const int xy = swzy(arow);
#pragma unroll
        for (int nt = 0; nt < 4; ++nt) {
            int col = cb + nt * 16 + kgrp * 4;
            f32x4 fb = *(const f32x4*)(ffn_b + col);
            pack4_u hp;
            hp.ll = *(const unsigned long long*)(hb16 + growc * DIM + col);
            f32x4 y;
#pragma unroll
            for (int j = 0; j < 4; ++j)
                y[j] = acc2[nt][j] + fb[j] + __bfloat162float(hp.b[j]);
            *(f32x4*)(aggy + arow * 512 + ((col * 4) ^ xy)) = y;
        }
    }
    __syncthreads();

    // ---- E: LayerNorm. Read swizzled ADDRESS; column is PRE-swizzle 2l. ----
#pragma unroll 1
    for (int jr = 0; jr < 8; ++jr) {
        const int row = wv * 8 + jr;
        const int n = n0 + row;
        const int x = swzy(row);
        float2 yv = *(const float2*)(aggy + row * 512 + ((l * 8) ^ x));
        const int col = l * 2;
        float s = yv.x + yv.y, s2 = yv.x * yv.x + yv.y * yv.y;
#pragma unroll
        for (int m = 1; m < 64; m <<= 1) {
            s  += __shfl_xor(s, m);
            s2 += __shfl_xor(s2, m);
        }
        if (n < N_NODES) {
            float mu  = s * (1.f / DIM);
            float var = s2 * (1.f / DIM) - mu * mu;
            float inv = rsqrtf(var + 1e-8f);
            float2 gv = *(const float2*)(ln_g + col);
            float2 bv = *(const float2*)(ln_b + col);
            float2 o2{(yv.x - mu) * inv * gv.x + bv.x,
                      (yv.y - mu) * inv * gv.y + bv.y};
            *(float2*)(out + (long long)n * DIM + col) = o2;
        }
    }
}

// ---------------------------------------------------------------------------
extern "C" void kernel_launch(void* const* d_in, const int* in_sizes, int n_in,
                              void* d_out, int out_size, void* d_ws, size_t ws_size,
                              hipStream_t stream) {
    const float* h      = (const float*)d_in[0];
    const float* V      = (const float*)d_in[1];
    const float* w_comp = (const float*)d_in[2];
    const float* loop_w = (const float*)d_in[3];
    const float* bias   = (const float*)d_in[4];
    const float* ffn_w  = (const float*)d_in[5];
    const float* ffn_b  = (const float*)d_in[6];
    const float* ln_g   = (const float*)d_in[7];
    const float* ln_b   = (const float*)d_in[8];
    const float* norm   = (const float*)d_in[9];
    const int*   src    = (const int*)d_in[10];
    const int*   dst    = (const int*)d_in[11];
    const int*   etype  = (const int*)d_in[12];
    float* out = (float*)d_out;

    if (ws_size < (size_t)WS_NEEDED) return;

    char* ws = (char*)d_ws;
    bf16*  Hr   = (bf16*)(ws + HR_OFF);
    bf16*  hb16 = (bf16*)(ws + HB16_OFF);
    uint2* recs = (uint2*)(ws + RECS_OFF);
    int*   base = (int*)(ws + BASE_OFF);
    int*   cur  = (int*)(ws + CUR_OFF);
    bf16*  WrT  = (bf16*)(ws + WRT_OFF);
    bf16*  lwT  = (bf16*)(ws + LWT_OFF);
    bf16*  fwTb = (bf16*)(ws + FWT_OFF);

    hipMemsetAsync(cur, 0, N_NODES * sizeof(int), stream);

    k_prep<<<dim3(3125), dim3(256), 0, stream>>>(
        h, V, w_comp, loop_w, ffn_w, dst, hb16, WrT, lwT, fwTb, cur);

    k_scan<<<dim3(1), dim3(1024), 0, stream>>>(cur, base);
    k_scatter<<<dim3((N_EDGES + 255) / 256), dim3(256), 0, stream>>>(
        src, dst, etype, norm, cur, recs);

    k_gemm<<<dim3((N_NODES + 127) / 128, NREL), dim3(256), 0, stream>>>(
        hb16, WrT, Hr);

    k_final<<<dim3((N_NODES + 31) / 32), dim3(256), 0, stream>>>(
        hb16, Hr, recs, base, lwT, bias, fwTb, ffn_b, ln_g, ln_b, out);
}